// Round 17
// baseline (134.576 us; speedup 1.0000x reference)
//
#include <hip/hip_runtime.h>
#include <hip/hip_fp16.h>
#include <math.h>

#define N_NODES 50000
#define E_EDGES 800000
#define IN_CH   128
#define OUT_CH  128   // HEADS*HID
#define HID     64
#define NEG_SLOPE 0.2f
#define NBLK_SCAN ((N_NODES + 255) / 256)   // 196
#define XS_STRIDE 136                       // 128 + 8 fp16 pad (272B rows)

typedef _Float16 half8 __attribute__((ext_vector_type(8)));
typedef _Float16 h2 __attribute__((ext_vector_type(2)));
typedef float f32x2 __attribute__((ext_vector_type(2)));
typedef float f32x4 __attribute__((ext_vector_type(4)));

// DPP rotation-reduce step within each 16-lane row: a += row_ror<N>(a).
template<int CTRL>
__device__ __forceinline__ float dpp_add(float a) {
    int t = __builtin_amdgcn_update_dpp(0, __float_as_int(a), CTRL, 0xF, 0xF, true);
    return a + __int_as_float(t);
}
#define REDUCE16(a)                                                          \
    a = dpp_add<0x128>(a); a = dpp_add<0x124>(a);                            \
    a = dpp_add<0x122>(a); a = dpp_add<0x121>(a);

// ============ prep: W in MFMA-fragment order + bcat + zero counts/done ============
__global__ __launch_bounds__(256) void convW_kernel(
    const float* __restrict__ Wl, const float* __restrict__ bl,
    const float* __restrict__ Wr, const float* __restrict__ br,
    __half* __restrict__ wfrag, float* __restrict__ bcat,
    int* __restrict__ counts, int* __restrict__ done) {
    const int gid = blockIdx.x * 256 + threadIdx.x;
    if (gid < N_NODES) counts[gid] = 0;
    if (gid == 0) *done = 0;
    if (gid >= 4096) return;
    const int n = gid & 255;          // output col in [0,256)
    const int c = gid >> 8;           // k-chunk in [0,16)
    const int t = n >> 4, q16 = n & 15, s = c >> 2, kg = c & 3;
    const int k0 = c * 8;
    const float* __restrict__ Wsrc = (n < 128) ? Wl : Wr;
    const int col = n & 127;
    half8 h;
    #pragma unroll
    for (int j = 0; j < 8; ++j) h[j] = (_Float16)Wsrc[(k0 + j) * 128 + col];
    ((half8*)wfrag)[((t * 4 + s) * 4 + kg) * 16 + q16] = h;
    if (c == 0) bcat[n] = (n < 128) ? bl[col] : br[col];
}

// ============ dense via MFMA + FUSED edge counting ============
// GEMM part: 4 waves, 64 nodes/block; wave wv owns output cols [wv*64,+64),
// B-frags hoisted to registers. After the epilogue each thread grid-strides
// edge pairs doing degree counting (overlaps with other blocks' GEMM work).
__global__ __launch_bounds__(256) void linear_mfma_kernel(
    const float* __restrict__ x, const __half* __restrict__ wfrag,
    const float* __restrict__ bcat,
    __half* __restrict__ xl16, float* __restrict__ xr,
    const int* __restrict__ ei, int* __restrict__ counts, int* __restrict__ rank) {
    __shared__ __align__(16) __half xs[64 * XS_STRIDE];
    const int tid  = threadIdx.x;
    const int lane = tid & 63;
    const int wv   = tid >> 6;
    const int nodeBase = blockIdx.x * 64;

    {
        const float4* __restrict__ x4 = (const float4*)(x + (size_t)nodeBase * IN_CH);
        #pragma unroll
        for (int i = 0; i < 8; ++i) {
            const int idx = tid + i * 256;      // float4 index in [0,2048)
            const int row = idx >> 5;
            const int c   = (idx & 31) * 4;
            float4 v = {0.0f, 0.0f, 0.0f, 0.0f};
            if (nodeBase + row < N_NODES) v = x4[idx];
            __half2 h01 = __floats2half2_rn(v.x, v.y);
            __half2 h23 = __floats2half2_rn(v.z, v.w);
            uint2 pk;
            pk.x = *(unsigned int*)&h01;
            pk.y = *(unsigned int*)&h23;
            *(uint2*)&xs[row * XS_STRIDE + c] = pk;
        }
    }
    __syncthreads();

    const int q16 = lane & 15;
    const int kg  = lane >> 4;

    const half8* __restrict__ wf8 = (const half8*)wfrag;
    half8 b[4][4];
    #pragma unroll
    for (int t = 0; t < 4; ++t)
        #pragma unroll
        for (int s = 0; s < 4; ++s)
            b[t][s] = wf8[(((wv * 4 + t) * 4 + s) * 4 + kg) * 16 + q16];

    #pragma unroll
    for (int m = 0; m < 4; ++m) {
        f32x4 acc[4];
        #pragma unroll
        for (int t = 0; t < 4; ++t) acc[t] = (f32x4){0.0f, 0.0f, 0.0f, 0.0f};
        #pragma unroll
        for (int s = 0; s < 4; ++s) {
            const half8 a = *(const half8*)&xs[(m * 16 + q16) * XS_STRIDE + s * 32 + kg * 8];
            #pragma unroll
            for (int t = 0; t < 4; ++t)
                acc[t] = __builtin_amdgcn_mfma_f32_16x16x32_f16(a, b[t][s], acc[t], 0, 0, 0);
        }
        const int nodeRow0 = nodeBase + m * 16 + kg * 4;
        #pragma unroll
        for (int t = 0; t < 4; ++t) {
            const int col = wv * 64 + t * 16 + q16;
            const float bv = bcat[col];
            #pragma unroll
            for (int r = 0; r < 4; ++r) {
                const int node = nodeRow0 + r;
                if (node < N_NODES) {
                    const float v = acc[t][r] + bv;
                    if (col < 128) xl16[(size_t)node * 128 + col] = __float2half_rn(v);
                    else           xr[(size_t)node * 128 + (col - 128)] = v;
                }
            }
        }
    }

    // ---- fused degree count: grid-stride over edge pairs ----
    const int gtid = blockIdx.x * 256 + tid;
    const int nthr = gridDim.x * 256;
    for (int p = gtid; p * 2 < E_EDGES; p += nthr) {
        int2 dd = *(const int2*)(ei + E_EDGES + p * 2);
        int2 rr;
        rr.x = atomicAdd(&counts[dd.x], 1);
        rr.y = atomicAdd(&counts[dd.y], 1);
        *(int2*)(rank + p * 2) = rr;
    }
}

// ============ scan1 + fused scan2 (last-block pattern, all-atomic tops) ============
__global__ __launch_bounds__(256) void scan1_kernel(const int* __restrict__ counts,
                                                    int* __restrict__ off,
                                                    int* __restrict__ tops,
                                                    int* __restrict__ done) {
    __shared__ int s[256];
    __shared__ int ticket;
    int i = blockIdx.x * 256 + threadIdx.x;
    int v = (i < N_NODES) ? counts[i] : 0;
    s[threadIdx.x] = v;
    __syncthreads();
    for (int dlt = 1; dlt < 256; dlt <<= 1) {
        int t = (threadIdx.x >= dlt) ? s[threadIdx.x - dlt] : 0;
        __syncthreads();
        s[threadIdx.x] += t;
        __syncthreads();
    }
    if (i < N_NODES) off[i] = s[threadIdx.x] - v;   // exclusive within block
    if (threadIdx.x == 255) {
        atomicExch(&tops[blockIdx.x], s[255]);      // device-scope publish
        ticket = atomicAdd(done, 1);
    }
    __syncthreads();
    if (ticket == NBLK_SCAN - 1) {
        // last block: exclusive-scan tops in place (atomic reads -> coherent)
        int tv = (threadIdx.x < NBLK_SCAN) ? atomicAdd(&tops[threadIdx.x], 0) : 0;
        s[threadIdx.x] = tv;
        __syncthreads();
        for (int dlt = 1; dlt < 256; dlt <<= 1) {
            int t = (threadIdx.x >= dlt) ? s[threadIdx.x - dlt] : 0;
            __syncthreads();
            s[threadIdx.x] += t;
            __syncthreads();
        }
        if (threadIdx.x < NBLK_SCAN) atomicExch(&tops[threadIdx.x], s[threadIdx.x] - tv);
    }
}

// atomic-free scatter: pos = segment start + precomputed rank; 4 edges/thread
__global__ void scatter_kernel(const int* __restrict__ ei, const int* __restrict__ off,
                               const int* __restrict__ tops, const int* __restrict__ rank,
                               int* __restrict__ ssrc) {
    int t = blockIdx.x * blockDim.x + threadIdx.x;
    if (t * 4 >= E_EDGES) return;
    int4 d = *(const int4*)(ei + E_EDGES + t * 4);
    int4 s = *(const int4*)(ei + t * 4);
    int4 r = *(const int4*)(rank + t * 4);
    ssrc[tops[d.x >> 8] + off[d.x] + r.x] = s.x;
    ssrc[tops[d.y >> 8] + off[d.y] + r.y] = s.y;
    ssrc[tops[d.z >> 8] + off[d.z] + r.z] = s.z;
    ssrc[tops[d.w >> 8] + off[d.w] + r.w] = s.w;
}

// ============ fused per-node softmax aggregation (R15 best-known form) ============
// One wave per dst node, 4 edges per main iteration (2 per half-wave).
// Packed-fp16 score path (common-mode fp16 error cancels in softmax);
// fp32 accumulation; DPP row_ror reductions.
__global__ __launch_bounds__(256) void node_agg_kernel(
    const __half* __restrict__ xl16, const float* __restrict__ xr,
    const float* __restrict__ att,
    const int* __restrict__ off, const int* __restrict__ counts,
    const int* __restrict__ tops, const int* __restrict__ ssrc,
    const float* __restrict__ bias, float* __restrict__ out) {
    const int node = (blockIdx.x * blockDim.x + threadIdx.x) >> 6;
    const int lane = threadIdx.x & 63;
    if (node >= N_NODES) return;
    const int half = lane >> 5;
    const int cl   = lane & 31;

    const uint2* __restrict__ xlh = (const uint2*)xl16;
    const float4 xrv  = ((const float4*)xr)[node * 32 + cl];
    const float4 attv = ((const float4*)att)[cl];
    const h2 xr01  = {(_Float16)xrv.x, (_Float16)xrv.y};
    const h2 xr23  = {(_Float16)xrv.z, (_Float16)xrv.w};
    const h2 att01 = {(_Float16)attv.x, (_Float16)attv.y};
    const h2 att23 = {(_Float16)attv.z, (_Float16)attv.w};
    const h2 ns2   = {(_Float16)NEG_SLOPE, (_Float16)NEG_SLOPE};

    const int cnt = counts[node];
    const int o   = tops[node >> 8] + off[node];

    float d = 0.0f;
    float4 acc = {0.0f, 0.0f, 0.0f, 0.0f};

#define SCOREH(raw, aout)                                                    \
    {                                                                        \
        h2 v01 = *(h2*)&raw.x;                                               \
        h2 v23 = *(h2*)&raw.y;                                               \
        h2 s01 = v01 + xr01;                                                 \
        h2 s23 = v23 + xr23;                                                 \
        h2 l01 = __builtin_elementwise_max(s01, s01 * ns2);                  \
        h2 l23 = __builtin_elementwise_max(s23, s23 * ns2);                  \
        aout = __builtin_amdgcn_fdot2(l01, att01,                            \
               __builtin_amdgcn_fdot2(l23, att23, 0.0f, false), false);      \
    }
#define ACCUM(raw, wgt)                                                      \
    {                                                                        \
        f32x2 f01 = __builtin_convertvector(*(h2*)&raw.x, f32x2);            \
        f32x2 f23 = __builtin_convertvector(*(h2*)&raw.y, f32x2);            \
        d += wgt;                                                            \
        acc.x = fmaf(wgt, f01.x, acc.x);                                     \
        acc.y = fmaf(wgt, f01.y, acc.y);                                     \
        acc.z = fmaf(wgt, f23.x, acc.z);                                     \
        acc.w = fmaf(wgt, f23.y, acc.w);                                     \
    }

    int k = 0;
    for (; k + 4 <= cnt; k += 4) {
        const int sA = ssrc[o + k + half];
        const int sB = ssrc[o + k + 2 + half];
        const uint2 rA = xlh[sA * 32 + cl];
        const uint2 rB = xlh[sB * 32 + cl];
        float a0, a1;
        SCOREH(rA, a0);
        SCOREH(rB, a1);
        REDUCE16(a0);
        REDUCE16(a1);
        const float eA = __expf(a0);
        const float eB = __expf(a1);
        ACCUM(rA, eA);
        ACCUM(rB, eB);
    }
    for (; k < cnt; k += 2) {
        const int eidx = k + half;
        const bool valid = (eidx < cnt);
        const int src = ssrc[o + (valid ? eidx : 0)];
        const uint2 raw = xlh[src * 32 + cl];
        float a;
        SCOREH(raw, a);
        REDUCE16(a);
        const float ev = valid ? __expf(a) : 0.0f;
        ACCUM(raw, ev);
    }
#undef SCOREH
#undef ACCUM
    acc.x += __shfl_xor(acc.x, 32);
    acc.y += __shfl_xor(acc.y, 32);
    acc.z += __shfl_xor(acc.z, 32);
    acc.w += __shfl_xor(acc.w, 32);
    d     += __shfl_xor(d, 32);

    if (lane < 32) {
        const float4 bv = ((const float4*)bias)[cl];
        const float inv = 1.0f / (d + 1e-16f);
        float4 r;
        float t;
        t = __expf(2.0f * fmaf(acc.x, inv, bv.x)); r.x = (t - 1.0f) / (t + 1.0f);
        t = __expf(2.0f * fmaf(acc.y, inv, bv.y)); r.y = (t - 1.0f) / (t + 1.0f);
        t = __expf(2.0f * fmaf(acc.z, inv, bv.z)); r.z = (t - 1.0f) / (t + 1.0f);
        t = __expf(2.0f * fmaf(acc.w, inv, bv.w)); r.w = (t - 1.0f) / (t + 1.0f);
        ((float4*)out)[node * 32 + cl] = r;
    }
}

extern "C" void kernel_launch(void* const* d_in, const int* in_sizes, int n_in,
                              void* d_out, int out_size, void* d_ws, size_t ws_size,
                              hipStream_t stream) {
    const float* x    = (const float*)d_in[0];
    const int*   ei   = (const int*)d_in[1];
    // d_in[2] = edge_weight — unused by the reference
    const float* Wl   = (const float*)d_in[3];
    const float* bl   = (const float*)d_in[4];
    const float* Wr   = (const float*)d_in[5];
    const float* br   = (const float*)d_in[6];
    const float* att  = (const float*)d_in[7];
    const float* bias = (const float*)d_in[8];
    float* out = (float*)d_out;

    // workspace layout
    char* ws = (char*)d_ws;
    __half* xl16  = (__half*)ws;  ws += (size_t)N_NODES * OUT_CH * 2;
    float*  xr    = (float*)ws;   ws += (size_t)N_NODES * OUT_CH * 4;
    __half* wfrag = (__half*)ws;  ws += (size_t)256 * 128 * 2;
    float*  bcat  = (float*)ws;   ws += 256 * 4;
    int*   counts = (int*)ws;     ws += (size_t)N_NODES * 4;
    int*   off    = (int*)ws;     ws += (size_t)N_NODES * 4;
    int*   tops   = (int*)ws;     ws += 256 * 4;
    int*   done   = (int*)ws;     ws += 16;        // keep 16B alignment
    int*   rank   = (int*)ws;     ws += (size_t)E_EDGES * 4;
    int*   ssrc   = (int*)ws;     ws += (size_t)E_EDGES * 4;

    convW_kernel<<<NBLK_SCAN, 256, 0, stream>>>(Wl, bl, Wr, br, wfrag, bcat, counts, done);
    linear_mfma_kernel<<<(N_NODES + 63) / 64, 256, 0, stream>>>(
        x, wfrag, bcat, xl16, xr, ei, counts, rank);
    scan1_kernel<<<NBLK_SCAN, 256, 0, stream>>>(counts, off, tops, done);
    scatter_kernel<<<(E_EDGES / 4 + 255) / 256, 256, 0, stream>>>(ei, off, tops, rank, ssrc);
    node_agg_kernel<<<(N_NODES + 3) / 4, 256, 0, stream>>>(
        xl16, xr, att, off, counts, tops, ssrc, bias, out);
}

// Round 18
// 126.007 us; speedup vs baseline: 1.0680x; 1.0680x over previous
//
#include <hip/hip_runtime.h>
#include <hip/hip_fp16.h>
#include <math.h>

#define N_NODES 50000
#define E_EDGES 800000
#define IN_CH   128
#define OUT_CH  128   // HEADS*HID
#define HID     64
#define NEG_SLOPE 0.2f
#define NBLK_SCAN ((N_NODES + 255) / 256)   // 196
#define XS_STRIDE 136                       // 128 + 8 fp16 pad (272B rows)

typedef _Float16 half8 __attribute__((ext_vector_type(8)));
typedef _Float16 h2 __attribute__((ext_vector_type(2)));
typedef float f32x2 __attribute__((ext_vector_type(2)));
typedef float f32x4 __attribute__((ext_vector_type(4)));

// DPP rotation-reduce step within each 16-lane row: a += row_ror<N>(a).
template<int CTRL>
__device__ __forceinline__ float dpp_add(float a) {
    int t = __builtin_amdgcn_update_dpp(0, __float_as_int(a), CTRL, 0xF, 0xF, true);
    return a + __int_as_float(t);
}
#define REDUCE16(a)                                                          \
    a = dpp_add<0x128>(a); a = dpp_add<0x124>(a);                            \
    a = dpp_add<0x122>(a); a = dpp_add<0x121>(a);

// ============ prep: W in MFMA-fragment order + bcat + zero counts/done ============
__global__ __launch_bounds__(256) void convW_kernel(
    const float* __restrict__ Wl, const float* __restrict__ bl,
    const float* __restrict__ Wr, const float* __restrict__ br,
    __half* __restrict__ wfrag, float* __restrict__ bcat,
    int* __restrict__ counts, int* __restrict__ done) {
    const int gid = blockIdx.x * 256 + threadIdx.x;
    if (gid < N_NODES) counts[gid] = 0;
    if (gid == 0) *done = 0;
    if (gid >= 4096) return;
    const int n = gid & 255;          // output col in [0,256)
    const int c = gid >> 8;           // k-chunk in [0,16)
    const int t = n >> 4, q16 = n & 15, s = c >> 2, kg = c & 3;
    const int k0 = c * 8;
    const float* __restrict__ Wsrc = (n < 128) ? Wl : Wr;
    const int col = n & 127;
    half8 h;
    #pragma unroll
    for (int j = 0; j < 8; ++j) h[j] = (_Float16)Wsrc[(k0 + j) * 128 + col];
    ((half8*)wfrag)[((t * 4 + s) * 4 + kg) * 16 + q16] = h;
    if (c == 0) bcat[n] = (n < 128) ? bl[col] : br[col];
}

// ============ standalone count: 2 edges/thread, high-occupancy (8 VGPR) ============
// Fusing this into the GEMM kernel was a 14 µs regression (R17): value-returning
// atomics need many waves to hide L2 round-trips; the GEMM's LDS/VGPR footprint
// caps occupancy at ~31%. Keep it lean and separate.
__global__ void count_kernel(const int* __restrict__ ei, int* __restrict__ counts,
                             int* __restrict__ rank) {
    int t = blockIdx.x * blockDim.x + threadIdx.x;
    if (t * 2 < E_EDGES) {
        int2 d = *(const int2*)(ei + E_EDGES + t * 2);
        int2 r;
        r.x = atomicAdd(&counts[d.x], 1);
        r.y = atomicAdd(&counts[d.y], 1);
        *(int2*)(rank + t * 2) = r;
    }
}

// ============ dense via MFMA (pure, R15 form) ============
__global__ __launch_bounds__(256) void linear_mfma_kernel(
    const float* __restrict__ x, const __half* __restrict__ wfrag,
    const float* __restrict__ bcat,
    __half* __restrict__ xl16, float* __restrict__ xr) {
    __shared__ __align__(16) __half xs[64 * XS_STRIDE];
    const int tid  = threadIdx.x;
    const int lane = tid & 63;
    const int wv   = tid >> 6;
    const int nodeBase = blockIdx.x * 64;

    {
        const float4* __restrict__ x4 = (const float4*)(x + (size_t)nodeBase * IN_CH);
        #pragma unroll
        for (int i = 0; i < 8; ++i) {
            const int idx = tid + i * 256;      // float4 index in [0,2048)
            const int row = idx >> 5;
            const int c   = (idx & 31) * 4;
            float4 v = {0.0f, 0.0f, 0.0f, 0.0f};
            if (nodeBase + row < N_NODES) v = x4[idx];
            __half2 h01 = __floats2half2_rn(v.x, v.y);
            __half2 h23 = __floats2half2_rn(v.z, v.w);
            uint2 pk;
            pk.x = *(unsigned int*)&h01;
            pk.y = *(unsigned int*)&h23;
            *(uint2*)&xs[row * XS_STRIDE + c] = pk;
        }
    }
    __syncthreads();

    const int q16 = lane & 15;
    const int kg  = lane >> 4;

    const half8* __restrict__ wf8 = (const half8*)wfrag;
    half8 b[4][4];
    #pragma unroll
    for (int t = 0; t < 4; ++t)
        #pragma unroll
        for (int s = 0; s < 4; ++s)
            b[t][s] = wf8[(((wv * 4 + t) * 4 + s) * 4 + kg) * 16 + q16];

    #pragma unroll
    for (int m = 0; m < 4; ++m) {
        f32x4 acc[4];
        #pragma unroll
        for (int t = 0; t < 4; ++t) acc[t] = (f32x4){0.0f, 0.0f, 0.0f, 0.0f};
        #pragma unroll
        for (int s = 0; s < 4; ++s) {
            const half8 a = *(const half8*)&xs[(m * 16 + q16) * XS_STRIDE + s * 32 + kg * 8];
            #pragma unroll
            for (int t = 0; t < 4; ++t)
                acc[t] = __builtin_amdgcn_mfma_f32_16x16x32_f16(a, b[t][s], acc[t], 0, 0, 0);
        }
        const int nodeRow0 = nodeBase + m * 16 + kg * 4;
        #pragma unroll
        for (int t = 0; t < 4; ++t) {
            const int col = wv * 64 + t * 16 + q16;
            const float bv = bcat[col];
            #pragma unroll
            for (int r = 0; r < 4; ++r) {
                const int node = nodeRow0 + r;
                if (node < N_NODES) {
                    const float v = acc[t][r] + bv;
                    if (col < 128) xl16[(size_t)node * 128 + col] = __float2half_rn(v);
                    else           xr[(size_t)node * 128 + (col - 128)] = v;
                }
            }
        }
    }
}

// ============ scan1 + fused scan2 (last-block pattern, all-atomic tops) ============
__global__ __launch_bounds__(256) void scan1_kernel(const int* __restrict__ counts,
                                                    int* __restrict__ off,
                                                    int* __restrict__ tops,
                                                    int* __restrict__ done) {
    __shared__ int s[256];
    __shared__ int ticket;
    int i = blockIdx.x * 256 + threadIdx.x;
    int v = (i < N_NODES) ? counts[i] : 0;
    s[threadIdx.x] = v;
    __syncthreads();
    for (int dlt = 1; dlt < 256; dlt <<= 1) {
        int t = (threadIdx.x >= dlt) ? s[threadIdx.x - dlt] : 0;
        __syncthreads();
        s[threadIdx.x] += t;
        __syncthreads();
    }
    if (i < N_NODES) off[i] = s[threadIdx.x] - v;   // exclusive within block
    if (threadIdx.x == 255) {
        atomicExch(&tops[blockIdx.x], s[255]);      // device-scope publish
        ticket = atomicAdd(done, 1);
    }
    __syncthreads();
    if (ticket == NBLK_SCAN - 1) {
        // last block: exclusive-scan tops in place (atomic reads -> coherent)
        int tv = (threadIdx.x < NBLK_SCAN) ? atomicAdd(&tops[threadIdx.x], 0) : 0;
        s[threadIdx.x] = tv;
        __syncthreads();
        for (int dlt = 1; dlt < 256; dlt <<= 1) {
            int t = (threadIdx.x >= dlt) ? s[threadIdx.x - dlt] : 0;
            __syncthreads();
            s[threadIdx.x] += t;
            __syncthreads();
        }
        if (threadIdx.x < NBLK_SCAN) atomicExch(&tops[threadIdx.x], s[threadIdx.x] - tv);
    }
}

// atomic-free scatter: pos = segment start + precomputed rank; 4 edges/thread
__global__ void scatter_kernel(const int* __restrict__ ei, const int* __restrict__ off,
                               const int* __restrict__ tops, const int* __restrict__ rank,
                               int* __restrict__ ssrc) {
    int t = blockIdx.x * blockDim.x + threadIdx.x;
    if (t * 4 >= E_EDGES) return;
    int4 d = *(const int4*)(ei + E_EDGES + t * 4);
    int4 s = *(const int4*)(ei + t * 4);
    int4 r = *(const int4*)(rank + t * 4);
    ssrc[tops[d.x >> 8] + off[d.x] + r.x] = s.x;
    ssrc[tops[d.y >> 8] + off[d.y] + r.y] = s.y;
    ssrc[tops[d.z >> 8] + off[d.z] + r.z] = s.z;
    ssrc[tops[d.w >> 8] + off[d.w] + r.w] = s.w;
}

// ============ fused per-node softmax aggregation (best-known form) ============
__global__ __launch_bounds__(256) void node_agg_kernel(
    const __half* __restrict__ xl16, const float* __restrict__ xr,
    const float* __restrict__ att,
    const int* __restrict__ off, const int* __restrict__ counts,
    const int* __restrict__ tops, const int* __restrict__ ssrc,
    const float* __restrict__ bias, float* __restrict__ out) {
    const int node = (blockIdx.x * blockDim.x + threadIdx.x) >> 6;
    const int lane = threadIdx.x & 63;
    if (node >= N_NODES) return;
    const int half = lane >> 5;
    const int cl   = lane & 31;

    const uint2* __restrict__ xlh = (const uint2*)xl16;
    const float4 xrv  = ((const float4*)xr)[node * 32 + cl];
    const float4 attv = ((const float4*)att)[cl];
    const h2 xr01  = {(_Float16)xrv.x, (_Float16)xrv.y};
    const h2 xr23  = {(_Float16)xrv.z, (_Float16)xrv.w};
    const h2 att01 = {(_Float16)attv.x, (_Float16)attv.y};
    const h2 att23 = {(_Float16)attv.z, (_Float16)attv.w};
    const h2 ns2   = {(_Float16)NEG_SLOPE, (_Float16)NEG_SLOPE};

    const int cnt = counts[node];
    const int o   = tops[node >> 8] + off[node];

    float d = 0.0f;
    float4 acc = {0.0f, 0.0f, 0.0f, 0.0f};

#define SCOREH(raw, aout)                                                    \
    {                                                                        \
        h2 v01 = *(h2*)&raw.x;                                               \
        h2 v23 = *(h2*)&raw.y;                                               \
        h2 s01 = v01 + xr01;                                                 \
        h2 s23 = v23 + xr23;                                                 \
        h2 l01 = __builtin_elementwise_max(s01, s01 * ns2);                  \
        h2 l23 = __builtin_elementwise_max(s23, s23 * ns2);                  \
        aout = __builtin_amdgcn_fdot2(l01, att01,                            \
               __builtin_amdgcn_fdot2(l23, att23, 0.0f, false), false);      \
    }
#define ACCUM(raw, wgt)                                                      \
    {                                                                        \
        f32x2 f01 = __builtin_convertvector(*(h2*)&raw.x, f32x2);            \
        f32x2 f23 = __builtin_convertvector(*(h2*)&raw.y, f32x2);            \
        d += wgt;                                                            \
        acc.x = fmaf(wgt, f01.x, acc.x);                                     \
        acc.y = fmaf(wgt, f01.y, acc.y);                                     \
        acc.z = fmaf(wgt, f23.x, acc.z);                                     \
        acc.w = fmaf(wgt, f23.y, acc.w);                                     \
    }

    int k = 0;
    for (; k + 4 <= cnt; k += 4) {
        const int sA = ssrc[o + k + half];
        const int sB = ssrc[o + k + 2 + half];
        const uint2 rA = xlh[sA * 32 + cl];
        const uint2 rB = xlh[sB * 32 + cl];
        float a0, a1;
        SCOREH(rA, a0);
        SCOREH(rB, a1);
        REDUCE16(a0);
        REDUCE16(a1);
        const float eA = __expf(a0);
        const float eB = __expf(a1);
        ACCUM(rA, eA);
        ACCUM(rB, eB);
    }
    for (; k < cnt; k += 2) {
        const int eidx = k + half;
        const bool valid = (eidx < cnt);
        const int src = ssrc[o + (valid ? eidx : 0)];
        const uint2 raw = xlh[src * 32 + cl];
        float a;
        SCOREH(raw, a);
        REDUCE16(a);
        const float ev = valid ? __expf(a) : 0.0f;
        ACCUM(raw, ev);
    }
#undef SCOREH
#undef ACCUM
    acc.x += __shfl_xor(acc.x, 32);
    acc.y += __shfl_xor(acc.y, 32);
    acc.z += __shfl_xor(acc.z, 32);
    acc.w += __shfl_xor(acc.w, 32);
    d     += __shfl_xor(d, 32);

    if (lane < 32) {
        const float4 bv = ((const float4*)bias)[cl];
        const float inv = 1.0f / (d + 1e-16f);
        float4 r;
        float t;
        t = __expf(2.0f * fmaf(acc.x, inv, bv.x)); r.x = (t - 1.0f) / (t + 1.0f);
        t = __expf(2.0f * fmaf(acc.y, inv, bv.y)); r.y = (t - 1.0f) / (t + 1.0f);
        t = __expf(2.0f * fmaf(acc.z, inv, bv.z)); r.z = (t - 1.0f) / (t + 1.0f);
        t = __expf(2.0f * fmaf(acc.w, inv, bv.w)); r.w = (t - 1.0f) / (t + 1.0f);
        ((float4*)out)[node * 32 + cl] = r;
    }
}

extern "C" void kernel_launch(void* const* d_in, const int* in_sizes, int n_in,
                              void* d_out, int out_size, void* d_ws, size_t ws_size,
                              hipStream_t stream) {
    const float* x    = (const float*)d_in[0];
    const int*   ei   = (const int*)d_in[1];
    // d_in[2] = edge_weight — unused by the reference
    const float* Wl   = (const float*)d_in[3];
    const float* bl   = (const float*)d_in[4];
    const float* Wr   = (const float*)d_in[5];
    const float* br   = (const float*)d_in[6];
    const float* att  = (const float*)d_in[7];
    const float* bias = (const float*)d_in[8];
    float* out = (float*)d_out;

    // workspace layout
    char* ws = (char*)d_ws;
    __half* xl16  = (__half*)ws;  ws += (size_t)N_NODES * OUT_CH * 2;
    float*  xr    = (float*)ws;   ws += (size_t)N_NODES * OUT_CH * 4;
    __half* wfrag = (__half*)ws;  ws += (size_t)256 * 128 * 2;
    float*  bcat  = (float*)ws;   ws += 256 * 4;
    int*   counts = (int*)ws;     ws += (size_t)N_NODES * 4;
    int*   off    = (int*)ws;     ws += (size_t)N_NODES * 4;
    int*   tops   = (int*)ws;     ws += 256 * 4;
    int*   done   = (int*)ws;     ws += 16;        // keep 16B alignment
    int*   rank   = (int*)ws;     ws += (size_t)E_EDGES * 4;
    int*   ssrc   = (int*)ws;     ws += (size_t)E_EDGES * 4;

    const int pairBlocks = (E_EDGES / 2 + 255) / 256;     // 1563

    convW_kernel<<<NBLK_SCAN, 256, 0, stream>>>(Wl, bl, Wr, br, wfrag, bcat, counts, done);
    linear_mfma_kernel<<<(N_NODES + 63) / 64, 256, 0, stream>>>(x, wfrag, bcat, xl16, xr);
    count_kernel<<<pairBlocks, 256, 0, stream>>>(ei, counts, rank);
    scan1_kernel<<<NBLK_SCAN, 256, 0, stream>>>(counts, off, tops, done);
    scatter_kernel<<<(E_EDGES / 4 + 255) / 256, 256, 0, stream>>>(ei, off, tops, rank, ssrc);
    node_agg_kernel<<<(N_NODES + 3) / 4, 256, 0, stream>>>(
        xl16, xr, att, off, counts, tops, ssrc, bias, out);
}

// Round 19
// 121.814 us; speedup vs baseline: 1.1048x; 1.0344x over previous
//
#include <hip/hip_runtime.h>
#include <hip/hip_fp16.h>
#include <math.h>

#define N_NODES 50000
#define E_EDGES 800000
#define IN_CH   128
#define OUT_CH  128   // HEADS*HID
#define HID     64
#define NEG_SLOPE 0.2f
#define NBLK_SCAN ((N_NODES + 255) / 256)   // 196
#define XS_STRIDE 136                       // 128 + 8 fp16 pad (272B rows)

typedef _Float16 half8 __attribute__((ext_vector_type(8)));
typedef _Float16 h2 __attribute__((ext_vector_type(2)));
typedef float f32x2 __attribute__((ext_vector_type(2)));
typedef float f32x4 __attribute__((ext_vector_type(4)));

// DPP add: a += dpp_perm(a). Pure VALU.
template<int CTRL>
__device__ __forceinline__ float dpp_add(float a) {
    int t = __builtin_amdgcn_update_dpp(0, __float_as_int(a), CTRL, 0xF, 0xF, true);
    return a + __int_as_float(t);
}
// 8-lane segment sum (within each half of a 16-lane DPP row):
// xor1 = quad_perm[1,0,3,2] (0xB1), xor2 = quad_perm[2,3,0,1] (0x4E),
// cross-quad = row_half_mirror (0x141). All DPP, no LDS pipe.
#define REDUCE8(a)                                                           \
    a = dpp_add<0xB1>(a); a = dpp_add<0x4E>(a); a = dpp_add<0x141>(a);

// ============ prep: W in MFMA-fragment order + bcat + zero counts/done ============
__global__ __launch_bounds__(256) void convW_kernel(
    const float* __restrict__ Wl, const float* __restrict__ bl,
    const float* __restrict__ Wr, const float* __restrict__ br,
    __half* __restrict__ wfrag, float* __restrict__ bcat,
    int* __restrict__ counts, int* __restrict__ done) {
    const int gid = blockIdx.x * 256 + threadIdx.x;
    if (gid < N_NODES) counts[gid] = 0;
    if (gid == 0) *done = 0;
    if (gid >= 4096) return;
    const int n = gid & 255;          // output col in [0,256)
    const int c = gid >> 8;           // k-chunk in [0,16)
    const int t = n >> 4, q16 = n & 15, s = c >> 2, kg = c & 3;
    const int k0 = c * 8;
    const float* __restrict__ Wsrc = (n < 128) ? Wl : Wr;
    const int col = n & 127;
    half8 h;
    #pragma unroll
    for (int j = 0; j < 8; ++j) h[j] = (_Float16)Wsrc[(k0 + j) * 128 + col];
    ((half8*)wfrag)[((t * 4 + s) * 4 + kg) * 16 + q16] = h;
    if (c == 0) bcat[n] = (n < 128) ? bl[col] : br[col];
}

// ============ standalone count: 2 edges/thread, high-occupancy ============
__global__ void count_kernel(const int* __restrict__ ei, int* __restrict__ counts,
                             int* __restrict__ rank) {
    int t = blockIdx.x * blockDim.x + threadIdx.x;
    if (t * 2 < E_EDGES) {
        int2 d = *(const int2*)(ei + E_EDGES + t * 2);
        int2 r;
        r.x = atomicAdd(&counts[d.x], 1);
        r.y = atomicAdd(&counts[d.y], 1);
        *(int2*)(rank + t * 2) = r;
    }
}

// ============ dense via MFMA: [xl16|xr16] = x @ [Wl|Wr] + [bl|br] (both fp16) ============
__global__ __launch_bounds__(256) void linear_mfma_kernel(
    const float* __restrict__ x, const __half* __restrict__ wfrag,
    const float* __restrict__ bcat,
    __half* __restrict__ xl16, __half* __restrict__ xr16) {
    __shared__ __align__(16) __half xs[64 * XS_STRIDE];
    const int tid  = threadIdx.x;
    const int lane = tid & 63;
    const int wv   = tid >> 6;
    const int nodeBase = blockIdx.x * 64;

    {
        const float4* __restrict__ x4 = (const float4*)(x + (size_t)nodeBase * IN_CH);
        #pragma unroll
        for (int i = 0; i < 8; ++i) {
            const int idx = tid + i * 256;      // float4 index in [0,2048)
            const int row = idx >> 5;
            const int c   = (idx & 31) * 4;
            float4 v = {0.0f, 0.0f, 0.0f, 0.0f};
            if (nodeBase + row < N_NODES) v = x4[idx];
            __half2 h01 = __floats2half2_rn(v.x, v.y);
            __half2 h23 = __floats2half2_rn(v.z, v.w);
            uint2 pk;
            pk.x = *(unsigned int*)&h01;
            pk.y = *(unsigned int*)&h23;
            *(uint2*)&xs[row * XS_STRIDE + c] = pk;
        }
    }
    __syncthreads();

    const int q16 = lane & 15;
    const int kg  = lane >> 4;

    const half8* __restrict__ wf8 = (const half8*)wfrag;
    half8 b[4][4];
    #pragma unroll
    for (int t = 0; t < 4; ++t)
        #pragma unroll
        for (int s = 0; s < 4; ++s)
            b[t][s] = wf8[(((wv * 4 + t) * 4 + s) * 4 + kg) * 16 + q16];

    #pragma unroll
    for (int m = 0; m < 4; ++m) {
        f32x4 acc[4];
        #pragma unroll
        for (int t = 0; t < 4; ++t) acc[t] = (f32x4){0.0f, 0.0f, 0.0f, 0.0f};
        #pragma unroll
        for (int s = 0; s < 4; ++s) {
            const half8 a = *(const half8*)&xs[(m * 16 + q16) * XS_STRIDE + s * 32 + kg * 8];
            #pragma unroll
            for (int t = 0; t < 4; ++t)
                acc[t] = __builtin_amdgcn_mfma_f32_16x16x32_f16(a, b[t][s], acc[t], 0, 0, 0);
        }
        const int nodeRow0 = nodeBase + m * 16 + kg * 4;
        #pragma unroll
        for (int t = 0; t < 4; ++t) {
            const int col = wv * 64 + t * 16 + q16;
            const float bv = bcat[col];
            __half* __restrict__ dstp = (col < 128) ? xl16 : xr16;
            const int dcol = col & 127;
            #pragma unroll
            for (int r = 0; r < 4; ++r) {
                const int node = nodeRow0 + r;
                if (node < N_NODES)
                    dstp[(size_t)node * 128 + dcol] = __float2half_rn(acc[t][r] + bv);
            }
        }
    }
}

// ============ scan1 + fused scan2 (last-block pattern, all-atomic tops) ============
__global__ __launch_bounds__(256) void scan1_kernel(const int* __restrict__ counts,
                                                    int* __restrict__ off,
                                                    int* __restrict__ tops,
                                                    int* __restrict__ done) {
    __shared__ int s[256];
    __shared__ int ticket;
    int i = blockIdx.x * 256 + threadIdx.x;
    int v = (i < N_NODES) ? counts[i] : 0;
    s[threadIdx.x] = v;
    __syncthreads();
    for (int dlt = 1; dlt < 256; dlt <<= 1) {
        int t = (threadIdx.x >= dlt) ? s[threadIdx.x - dlt] : 0;
        __syncthreads();
        s[threadIdx.x] += t;
        __syncthreads();
    }
    if (i < N_NODES) off[i] = s[threadIdx.x] - v;   // exclusive within block
    if (threadIdx.x == 255) {
        atomicExch(&tops[blockIdx.x], s[255]);      // device-scope publish
        ticket = atomicAdd(done, 1);
    }
    __syncthreads();
    if (ticket == NBLK_SCAN - 1) {
        int tv = (threadIdx.x < NBLK_SCAN) ? atomicAdd(&tops[threadIdx.x], 0) : 0;
        s[threadIdx.x] = tv;
        __syncthreads();
        for (int dlt = 1; dlt < 256; dlt <<= 1) {
            int t = (threadIdx.x >= dlt) ? s[threadIdx.x - dlt] : 0;
            __syncthreads();
            s[threadIdx.x] += t;
            __syncthreads();
        }
        if (threadIdx.x < NBLK_SCAN) atomicExch(&tops[threadIdx.x], s[threadIdx.x] - tv);
    }
}

// atomic-free scatter: pos = segment start + precomputed rank; 4 edges/thread
__global__ void scatter_kernel(const int* __restrict__ ei, const int* __restrict__ off,
                               const int* __restrict__ tops, const int* __restrict__ rank,
                               int* __restrict__ ssrc) {
    int t = blockIdx.x * blockDim.x + threadIdx.x;
    if (t * 4 >= E_EDGES) return;
    int4 d = *(const int4*)(ei + E_EDGES + t * 4);
    int4 s = *(const int4*)(ei + t * 4);
    int4 r = *(const int4*)(rank + t * 4);
    ssrc[tops[d.x >> 8] + off[d.x] + r.x] = s.x;
    ssrc[tops[d.y >> 8] + off[d.y] + r.y] = s.y;
    ssrc[tops[d.z >> 8] + off[d.z] + r.z] = s.z;
    ssrc[tops[d.w >> 8] + off[d.w] + r.w] = s.w;
}

// ============ fused per-node softmax aggregation — 16-lane-per-edge ============
// One wave per dst node; quarter-wave qw = lane>>4 owns one edge per gather
// instruction (4 edges per wave-load, uint4 = 16B/lane -> halved VMEM instrs).
// Lane ql = lane&15 covers channels 8ql..8ql+7; head0 = ql 0-7, head1 = ql 8-15.
// Score reduce = 3 pure-DPP steps (quad_perm xor1/xor2 + row_half_mirror).
__global__ __launch_bounds__(256) void node_agg_kernel(
    const __half* __restrict__ xl16, const __half* __restrict__ xr16,
    const float* __restrict__ att,
    const int* __restrict__ off, const int* __restrict__ counts,
    const int* __restrict__ tops, const int* __restrict__ ssrc,
    const float* __restrict__ bias, float* __restrict__ out) {
    const int node = (blockIdx.x * blockDim.x + threadIdx.x) >> 6;
    const int lane = threadIdx.x & 63;
    if (node >= N_NODES) return;
    const int qw = lane >> 4;
    const int ql = lane & 15;

    const uint4* __restrict__ xlh = (const uint4*)xl16;
    const uint4 xq = ((const uint4*)xr16)[node * 16 + ql];
    const h2 xq0 = *(h2*)&xq.x, xq1 = *(h2*)&xq.y, xq2 = *(h2*)&xq.z, xq3 = *(h2*)&xq.w;
    const float4 atA = ((const float4*)att)[ql * 2];
    const float4 atB = ((const float4*)att)[ql * 2 + 1];
    const h2 at0 = {(_Float16)atA.x, (_Float16)atA.y};
    const h2 at1 = {(_Float16)atA.z, (_Float16)atA.w};
    const h2 at2 = {(_Float16)atB.x, (_Float16)atB.y};
    const h2 at3 = {(_Float16)atB.z, (_Float16)atB.w};
    const h2 ns2 = {(_Float16)NEG_SLOPE, (_Float16)NEG_SLOPE};

    const int cnt = counts[node];
    const int o   = tops[node >> 8] + off[node];

    float d = 0.0f;
    float av[8] = {0.0f, 0.0f, 0.0f, 0.0f, 0.0f, 0.0f, 0.0f, 0.0f};

#define SCOREH(rq, aout)                                                     \
    {                                                                        \
        h2 v0 = *(h2*)&rq.x, v1 = *(h2*)&rq.y, v2 = *(h2*)&rq.z, v3 = *(h2*)&rq.w; \
        h2 s0 = v0 + xq0, s1 = v1 + xq1, s2 = v2 + xq2, s3 = v3 + xq3;       \
        h2 l0 = __builtin_elementwise_max(s0, s0 * ns2);                     \
        h2 l1 = __builtin_elementwise_max(s1, s1 * ns2);                     \
        h2 l2 = __builtin_elementwise_max(s2, s2 * ns2);                     \
        h2 l3 = __builtin_elementwise_max(s3, s3 * ns2);                     \
        aout = __builtin_amdgcn_fdot2(l0, at0,                               \
               __builtin_amdgcn_fdot2(l1, at1,                               \
               __builtin_amdgcn_fdot2(l2, at2,                               \
               __builtin_amdgcn_fdot2(l3, at3, 0.0f, false), false), false), false); \
    }
#define ACCUM(rq, wgt)                                                       \
    {                                                                        \
        f32x2 f0 = __builtin_convertvector(*(h2*)&rq.x, f32x2);              \
        f32x2 f1 = __builtin_convertvector(*(h2*)&rq.y, f32x2);              \
        f32x2 f2 = __builtin_convertvector(*(h2*)&rq.z, f32x2);              \
        f32x2 f3 = __builtin_convertvector(*(h2*)&rq.w, f32x2);              \
        d += wgt;                                                            \
        av[0] = fmaf(wgt, f0.x, av[0]); av[1] = fmaf(wgt, f0.y, av[1]);      \
        av[2] = fmaf(wgt, f1.x, av[2]); av[3] = fmaf(wgt, f1.y, av[3]);      \
        av[4] = fmaf(wgt, f2.x, av[4]); av[5] = fmaf(wgt, f2.y, av[5]);      \
        av[6] = fmaf(wgt, f3.x, av[6]); av[7] = fmaf(wgt, f3.y, av[7]);      \
    }

    int k = 0;
    // main: 8 edges per iteration (2 independent 4-edge wave-loads)
    for (; k + 8 <= cnt; k += 8) {
        const int iA = ssrc[o + k + qw];
        const int iB = ssrc[o + k + 4 + qw];
        const uint4 rA = xlh[iA * 16 + ql];
        const uint4 rB = xlh[iB * 16 + ql];
        float a0, a1;
        SCOREH(rA, a0);
        SCOREH(rB, a1);
        REDUCE8(a0);
        REDUCE8(a1);
        const float eA = __expf(a0);
        const float eB = __expf(a1);
        ACCUM(rA, eA);
        ACCUM(rB, eB);
    }
    // tail: 4-edge predicated steps
    for (; k < cnt; k += 4) {
        const int e = k + qw;
        const bool valid = (e < cnt);
        const int idx = ssrc[o + (valid ? e : 0)];
        const uint4 rq = xlh[idx * 16 + ql];
        float a;
        SCOREH(rq, a);
        REDUCE8(a);
        const float ev = valid ? __expf(a) : 0.0f;
        ACCUM(rq, ev);
    }
#undef SCOREH
#undef ACCUM
    // combine the four quarter-wave partial sums
    #pragma unroll
    for (int j = 0; j < 8; ++j) {
        av[j] += __shfl_xor(av[j], 16);
        av[j] += __shfl_xor(av[j], 32);
    }
    d += __shfl_xor(d, 16);
    d += __shfl_xor(d, 32);

    if (qw == 0) {
        const float4 b0 = ((const float4*)bias)[ql * 2];
        const float4 b1 = ((const float4*)bias)[ql * 2 + 1];
        const float inv = 1.0f / (d + 1e-16f);
        float4 r0, r1;
        float t;
        t = __expf(2.0f * fmaf(av[0], inv, b0.x)); r0.x = (t - 1.0f) / (t + 1.0f);
        t = __expf(2.0f * fmaf(av[1], inv, b0.y)); r0.y = (t - 1.0f) / (t + 1.0f);
        t = __expf(2.0f * fmaf(av[2], inv, b0.z)); r0.z = (t - 1.0f) / (t + 1.0f);
        t = __expf(2.0f * fmaf(av[3], inv, b0.w)); r0.w = (t - 1.0f) / (t + 1.0f);
        t = __expf(2.0f * fmaf(av[4], inv, b1.x)); r1.x = (t - 1.0f) / (t + 1.0f);
        t = __expf(2.0f * fmaf(av[5], inv, b1.y)); r1.y = (t - 1.0f) / (t + 1.0f);
        t = __expf(2.0f * fmaf(av[6], inv, b1.z)); r1.z = (t - 1.0f) / (t + 1.0f);
        t = __expf(2.0f * fmaf(av[7], inv, b1.w)); r1.w = (t - 1.0f) / (t + 1.0f);
        *(float4*)(out + (size_t)node * 128 + ql * 8)     = r0;
        *(float4*)(out + (size_t)node * 128 + ql * 8 + 4) = r1;
    }
}

extern "C" void kernel_launch(void* const* d_in, const int* in_sizes, int n_in,
                              void* d_out, int out_size, void* d_ws, size_t ws_size,
                              hipStream_t stream) {
    const float* x    = (const float*)d_in[0];
    const int*   ei   = (const int*)d_in[1];
    // d_in[2] = edge_weight — unused by the reference
    const float* Wl   = (const float*)d_in[3];
    const float* bl   = (const float*)d_in[4];
    const float* Wr   = (const float*)d_in[5];
    const float* br   = (const float*)d_in[6];
    const float* att  = (const float*)d_in[7];
    const float* bias = (const float*)d_in[8];
    float* out = (float*)d_out;

    // workspace layout
    char* ws = (char*)d_ws;
    __half* xl16  = (__half*)ws;  ws += (size_t)N_NODES * OUT_CH * 2;
    __half* xr16  = (__half*)ws;  ws += (size_t)N_NODES * OUT_CH * 2;
    __half* wfrag = (__half*)ws;  ws += (size_t)256 * 128 * 2;
    float*  bcat  = (float*)ws;   ws += 256 * 4;
    int*   counts = (int*)ws;     ws += (size_t)N_NODES * 4;
    int*   off    = (int*)ws;     ws += (size_t)N_NODES * 4;
    int*   tops   = (int*)ws;     ws += 256 * 4;
    int*   done   = (int*)ws;     ws += 16;        // keep 16B alignment
    int*   rank   = (int*)ws;     ws += (size_t)E_EDGES * 4;
    int*   ssrc   = (int*)ws;     ws += (size_t)E_EDGES * 4;

    const int pairBlocks = (E_EDGES / 2 + 255) / 256;     // 1563

    convW_kernel<<<NBLK_SCAN, 256, 0, stream>>>(Wl, bl, Wr, br, wfrag, bcat, counts, done);
    linear_mfma_kernel<<<(N_NODES + 63) / 64, 256, 0, stream>>>(x, wfrag, bcat, xl16, xr16);
    count_kernel<<<pairBlocks, 256, 0, stream>>>(ei, counts, rank);
    scan1_kernel<<<NBLK_SCAN, 256, 0, stream>>>(counts, off, tops, done);
    scatter_kernel<<<(E_EDGES / 4 + 255) / 256, 256, 0, stream>>>(ei, off, tops, rank, ssrc);
    node_agg_kernel<<<(N_NODES + 3) / 4, 256, 0, stream>>>(
        xl16, xr16, att, off, counts, tops, ssrc, bias, out);
}